// Round 5
// baseline (169.873 us; speedup 1.0000x reference)
//
#include <hip/hip_runtime.h>
#include <math.h>

#define NCELLS 1024
#define HID 512
#define ODIM 256
#define NPAIRS 512

typedef __attribute__((ext_vector_type(4))) float f32x4;
typedef __attribute__((ext_vector_type(8))) short short8;
typedef unsigned short ushort_t;

__device__ inline float sigm(float x){ return 1.0f/(1.0f + expf(-x)); }
__device__ inline float tanh3(float x){ return x*fmaf(x*x, -0.33333334f, 1.0f); }
__device__ inline ushort_t f2bf(float f){
    unsigned u = __float_as_uint(f);
    return (ushort_t)((u + 0x7FFFu + ((u>>16)&1u)) >> 16);
}
__device__ inline short8 pack8(float4 v0, float4 v1){
    short8 o;
    o[0]=(short)f2bf(v0.x); o[1]=(short)f2bf(v0.y); o[2]=(short)f2bf(v0.z); o[3]=(short)f2bf(v0.w);
    o[4]=(short)f2bf(v1.x); o[5]=(short)f2bf(v1.y); o[6]=(short)f2bf(v1.z); o[7]=(short)f2bf(v1.w);
    return o;
}

// ============ K_CVTW: weights -> bf16 fragment order ============
// frag: dst[idx*64+lane] = src[rt*16+(lane&15)][kt*32+(lane>>4)*8 + 0..8), idx=rt*KT+kt
// tiles: Wc1 384 (KT=24) | Wc2 128 (KT=8) | wih 768 (KT=8) | whh 1536 (KT=16) = 2816
__global__ __launch_bounds__(256) void k_cvtw(
    const float* __restrict__ W1a, const float* __restrict__ W1g,
    const float* __restrict__ W2a, const float* __restrict__ W2g,
    const float* __restrict__ w_ih, const float* __restrict__ w_hh,
    const float* __restrict__ b1a, const float* __restrict__ b1g,
    const float* __restrict__ b2a, const float* __restrict__ b2g,
    ushort_t* __restrict__ Wc1f, ushort_t* __restrict__ Wc2f,
    ushort_t* __restrict__ wihf, ushort_t* __restrict__ whhf,
    float* __restrict__ bc1, float* __restrict__ bc2, float* __restrict__ wcol)
{
    const int t = threadIdx.x;
    if (blockIdx.x == 704){ // scalar tail: bc1(256) bc2(256) wcol(1536)
        #pragma unroll
        for (int i=0;i<8;++i){
            int id = i*256 + t;
            if (id < 256)      bc1[id] = (id<128) ? b1a[id] : b1g[id-128];
            else if (id < 512){ int k=id-256; bc2[k] = b2a[k] - b2g[k]; }
            else              { int k=id-512; wcol[k] = w_ih[(size_t)k*257 + 256]; }
        }
        return;
    }
    const int T = blockIdx.x*4 + (t>>6);
    const int lane = t & 63;
    int job, idx, KT; ushort_t* dst;
    if      (T < 384){  job=0; idx=T;      KT=24; dst=Wc1f; }
    else if (T < 512){  job=1; idx=T-384;  KT=8;  dst=Wc2f; }
    else if (T < 1280){ job=2; idx=T-512;  KT=8;  dst=wihf; }
    else             {  job=3; idx=T-1280; KT=16; dst=whhf; }
    const int rt = idx / KT, kt = idx % KT;
    const int r  = rt*16 + (lane & 15);
    const int kb = kt*32 + (lane >> 4)*8;
    float v[8];
    if (job == 0){
        const float* s = (r < 128) ? (W1a + (size_t)r*768 + kb) : (W1g + (size_t)(r-128)*768 + kb);
        #pragma unroll
        for (int j=0;j<8;++j) v[j] = s[j];
    } else if (job == 1){
        if (kb < 128){ const float* s = W2a + (size_t)r*128 + kb;
            #pragma unroll
            for (int j=0;j<8;++j) v[j] = s[j];
        } else { const float* s = W2g + (size_t)r*128 + (kb-128);
            #pragma unroll
            for (int j=0;j<8;++j) v[j] = -s[j];
        }
    } else if (job == 2){
        const float* s = w_ih + (size_t)r*257 + kb;
        #pragma unroll
        for (int j=0;j<8;++j) v[j] = s[j];
    } else {
        const float* s = w_hh + (size_t)r*512 + kb;
        #pragma unroll
        for (int j=0;j<8;++j) v[j] = s[j];
    }
    short8 o;
    #pragma unroll
    for (int j=0;j<8;++j) o[j] = (short)f2bf(v[j]);
    ((short8*)dst)[(size_t)idx*64 + lane] = o;
}

// ============ K_FWD: per-16-row fused MLP + GRU-gate GEMMs ============
// 64 blocks x 256 thr. Block owns cells r0..r0+16.
// phases: comb-frags -> L1 -> repack -> L2(OUT,tension,Of) -> GS/GIn/GHn
__global__ __launch_bounds__(256) void k_fwd(
    const float* __restrict__ x, const float* __restrict__ hiddens,
    const ushort_t* __restrict__ Wc1f, const ushort_t* __restrict__ Wc2f,
    const ushort_t* __restrict__ wihf, const ushort_t* __restrict__ whhf,
    const float* __restrict__ bc1, const float* __restrict__ bc2,
    const float* __restrict__ b_ih, const float* __restrict__ b_hh,
    float* __restrict__ OUT, float* __restrict__ tension,
    float* __restrict__ GS, float* __restrict__ GIn, float* __restrict__ GHn)
{
    const int r0 = blockIdx.x*16;
    const int t = threadIdx.x;
    const int lane = t & 63, w = t >> 6;
    __shared__ short8 lds_comb[24*64];   // comb bf16 frags (x | hiddens), kt 8..23 = hiddens part
    __shared__ short8 lds_h1[8*64];      // H1 bf16 frags
    __shared__ short8 lds_of[8*64];      // OUT bf16 frags
    __shared__ __align__(16) float lds_tile[16][264];
    const short8* B1 = (const short8*)Wc1f;
    const short8* B2 = (const short8*)Wc2f;
    const short8* Bi = (const short8*)wihf;
    const short8* Bh = (const short8*)whhf;

    // ---- phase 0: build comb frags from x / hiddens
    #pragma unroll
    for (int s6=0; s6<6; ++s6){
        int s = t + s6*256;              // 24*64 = 1536 slots
        int kt = s>>6, ln = s&63;
        int row = r0 + (ln&15);
        int cb = kt*32 + ((ln>>4)<<3);
        const float* src = (cb < 256) ? (x + cb) : (hiddens + (size_t)row*HID + (cb-256));
        float4 v0 = *(const float4*)src;
        float4 v1 = *(const float4*)(src+4);
        lds_comb[s] = pack8(v0, v1);
    }
    __syncthreads();

    // ---- phase 1: L1 = relu(comb @ Wc1^T + bc1), wave w -> cols w*64..+64
    {
        f32x4 acc[4] = {{0,0,0,0},{0,0,0,0},{0,0,0,0},{0,0,0,0}};
        for (int kt=0; kt<24; ++kt){
            short8 a = lds_comb[kt*64 + lane];
            #pragma unroll
            for (int c=0;c<4;++c){
                short8 b = B1[((w*4+c)*24 + kt)*64 + lane];
                acc[c] = __builtin_amdgcn_mfma_f32_16x16x32_bf16(a, b, acc[c], 0,0,0);
            }
        }
        const int rb = (lane>>4)*4;
        #pragma unroll
        for (int c=0;c<4;++c){
            int col = w*64 + c*16 + (lane&15);
            float bb = bc1[col];
            #pragma unroll
            for (int i=0;i<4;++i)
                lds_tile[rb+i][col] = fmaxf(acc[c][i] + bb, 0.f);
        }
    }
    __syncthreads();
    // ---- phase 2: repack H1 -> bf16 frags
    #pragma unroll
    for (int s2=0; s2<2; ++s2){
        int s = t + s2*256;              // 8*64 = 512 slots
        int ln = s&63;
        int row = ln&15, cb = (s>>6)*32 + ((ln>>4)<<3);
        float4 v0 = *(const float4*)&lds_tile[row][cb];
        float4 v1 = *(const float4*)&lds_tile[row][cb+4];
        lds_h1[s] = pack8(v0, v1);
    }
    __syncthreads();
    // ---- phase 3: L2: OUT = H1 @ Wc2^T + bc2
    {
        f32x4 acc[4] = {{0,0,0,0},{0,0,0,0},{0,0,0,0},{0,0,0,0}};
        for (int kt=0; kt<8; ++kt){
            short8 a = lds_h1[kt*64 + lane];
            #pragma unroll
            for (int c=0;c<4;++c){
                short8 b = B2[((w*4+c)*8 + kt)*64 + lane];
                acc[c] = __builtin_amdgcn_mfma_f32_16x16x32_bf16(a, b, acc[c], 0,0,0);
            }
        }
        const int rb = (lane>>4)*4;
        #pragma unroll
        for (int c=0;c<4;++c){
            int col = w*64 + c*16 + (lane&15);
            float bb = bc2[col];
            #pragma unroll
            for (int i=0;i<4;++i)
                lds_tile[rb+i][col] = acc[c][i] + bb;
        }
    }
    __syncthreads();
    // ---- phase 4a: tension (row mean of squares)
    {
        int row = t>>4, seg = t&15;
        float s = 0.f;
        #pragma unroll
        for (int c=0;c<16;++c){ float v = lds_tile[row][seg*16+c]; s = fmaf(v,v,s); }
        s += __shfl_xor(s,1); s += __shfl_xor(s,2); s += __shfl_xor(s,4); s += __shfl_xor(s,8);
        if (seg == 0) tension[r0+row] = s * (1.0f/ODIM);
    }
    // ---- phase 4b: write OUT f32
    #pragma unroll
    for (int s4=0; s4<4; ++s4){
        int s = t + s4*256;              // 16 rows x 64 float4
        int row = s>>6, c4 = s&63;
        float4 v = *(const float4*)&lds_tile[row][c4*4];
        *(float4*)&OUT[(size_t)(r0+row)*ODIM + c4*4] = v;
    }
    // ---- phase 4c: Of frags
    #pragma unroll
    for (int s2=0; s2<2; ++s2){
        int s = t + s2*256;
        int ln = s&63;
        int row = ln&15, cb = (s>>6)*32 + ((ln>>4)<<3);
        float4 v0 = *(const float4*)&lds_tile[row][cb];
        float4 v1 = *(const float4*)&lds_tile[row][cb+4];
        lds_of[s] = pack8(v0, v1);
    }
    __syncthreads();
    // ---- phase 5: gate GEMMs. gates n<1024: GS = gi+gh (both biases);
    //      n>=1024 (n-gate): GIn, GHn separate.
    const int rb = (lane>>4)*4;
    for (int c6=0; c6<6; ++c6){
        const int g = w + 4*c6;          // 0..23
        const int nt0 = g*4;             // gate n-tile base (of 96)
        if (nt0 < 64){
            f32x4 acc[4] = {{0,0,0,0},{0,0,0,0},{0,0,0,0},{0,0,0,0}};
            for (int kt=0; kt<8; ++kt){
                short8 a = lds_of[kt*64 + lane];
                #pragma unroll
                for (int c=0;c<4;++c){
                    short8 b = Bi[((nt0+c)*8 + kt)*64 + lane];
                    acc[c] = __builtin_amdgcn_mfma_f32_16x16x32_bf16(a, b, acc[c], 0,0,0);
                }
            }
            for (int kt=0; kt<16; ++kt){
                short8 a = lds_comb[(8+kt)*64 + lane];
                #pragma unroll
                for (int c=0;c<4;++c){
                    short8 b = Bh[((nt0+c)*16 + kt)*64 + lane];
                    acc[c] = __builtin_amdgcn_mfma_f32_16x16x32_bf16(a, b, acc[c], 0,0,0);
                }
            }
            #pragma unroll
            for (int c=0;c<4;++c){
                int n = (nt0+c)*16 + (lane&15);
                float bb = b_ih[n] + b_hh[n];
                #pragma unroll
                for (int i=0;i<4;++i)
                    GS[(size_t)(r0+rb+i)*1024 + n] = acc[c][i] + bb;
            }
        } else {
            f32x4 ai[4] = {{0,0,0,0},{0,0,0,0},{0,0,0,0},{0,0,0,0}};
            f32x4 ah[4] = {{0,0,0,0},{0,0,0,0},{0,0,0,0},{0,0,0,0}};
            for (int kt=0; kt<8; ++kt){
                short8 a = lds_of[kt*64 + lane];
                #pragma unroll
                for (int c=0;c<4;++c){
                    short8 b = Bi[((nt0+c)*8 + kt)*64 + lane];
                    ai[c] = __builtin_amdgcn_mfma_f32_16x16x32_bf16(a, b, ai[c], 0,0,0);
                }
            }
            for (int kt=0; kt<16; ++kt){
                short8 a = lds_comb[(8+kt)*64 + lane];
                #pragma unroll
                for (int c=0;c<4;++c){
                    short8 b = Bh[((nt0+c)*16 + kt)*64 + lane];
                    ah[c] = __builtin_amdgcn_mfma_f32_16x16x32_bf16(a, b, ah[c], 0,0,0);
                }
            }
            #pragma unroll
            for (int c=0;c<4;++c){
                int j = (nt0+c-64)*16 + (lane&15);
                float bi = b_ih[1024+j], bh = b_hh[1024+j];
                #pragma unroll
                for (int i=0;i<4;++i){
                    GIn[(size_t)(r0+rb+i)*HID + j] = ai[c][i] + bi;
                    GHn[(size_t)(r0+rb+i)*HID + j] = ah[c][i] + bh;
                }
            }
        }
    }
}

// ============ fused GRU + pair entanglement mixing ============
__global__ __launch_bounds__(512) void k_mix(const float* __restrict__ GS,
        const float* __restrict__ GIn, const float* __restrict__ GHn,
        const float* __restrict__ tension, const float* __restrict__ wcol,
        const float* __restrict__ hiddens,
        const float* __restrict__ bell, const float* __restrict__ ent,
        float* __restrict__ hmix)
{
    const int p = blockIdx.x;
    const int tid = threadIdx.x;
    const int lane = tid & 63;
    const int wv = tid >> 6;
    __shared__ __align__(16) float hi[HID], hj[HID];
    __shared__ __align__(16) float colacc[8][HID];
    // GRU epilogue for cells 2p (->hi) and 2p+1 (->hj)
    {
        const int j = tid;
        const float wj0 = wcol[j], wj1 = wcol[512+j], wj2 = wcol[1024+j];
        #pragma unroll
        for (int c01=0; c01<2; ++c01){
            const int cell = 2*p + c01;
            const float tv = tension[cell];
            const float* gs = GS + (size_t)cell*1024;
            float rg = sigm(gs[j]     + tv*wj0);
            float zg = sigm(gs[512+j] + tv*wj1);
            float nn = tanhf(GIn[(size_t)cell*HID + j] + tv*wj2 + rg*GHn[(size_t)cell*HID + j]);
            float h  = (1.f - zg)*nn + zg*hiddens[(size_t)cell*HID + j];
            (c01 ? hj : hi)[j] = h;
        }
    }
    __syncthreads();
    const float* __restrict__ rot = bell + (size_t)p * HID * HID;
    const float e = 1.0f/(1.0f + expf(-ent[p]));
    const float one_e = 1.0f - e;
    const int c0 = lane<<2, c1 = 256 + (lane<<2);
    float hjr[8];
    #pragma unroll
    for (int k=0;k<4;++k){ hjr[k]=hj[c0+k]; hjr[4+k]=hj[c1+k]; }
    float aj[8] = {};
    #pragma unroll 2
    for (int r = wv; r < HID; r += 8) {
        float4 v0 = *(const float4*)(rot + (size_t)r*HID + c0);
        float4 v1 = *(const float4*)(rot + (size_t)r*HID + c1);
        float tt[8];
        tt[0]=tanh3(v0.x); tt[1]=tanh3(v0.y); tt[2]=tanh3(v0.z); tt[3]=tanh3(v0.w);
        tt[4]=tanh3(v1.x); tt[5]=tanh3(v1.y); tt[6]=tanh3(v1.z); tt[7]=tanh3(v1.w);
        const float hir = hi[r];
        float rp = 0.0f;
        #pragma unroll
        for (int k=0;k<8;++k){ rp = fmaf(tt[k], hjr[k], rp); aj[k] = fmaf(tt[k], hir, aj[k]); }
        #pragma unroll
        for (int m=1;m<64;m<<=1) rp += __shfl_xor(rp, m);
        if (lane == 0) hmix[(size_t)(2*p)*HID + r] = one_e*hir + e*rp;
    }
    *(float4*)&colacc[wv][c0] = make_float4(aj[0],aj[1],aj[2],aj[3]);
    *(float4*)&colacc[wv][c1] = make_float4(aj[4],aj[5],aj[6],aj[7]);
    __syncthreads();
    float s = 0.0f;
    #pragma unroll
    for (int w=0;w<8;++w) s += colacc[w][tid];
    hmix[(size_t)(2*p+1)*HID + tid] = -(one_e*hj[tid] + e*s);
}

// ============ faction mean ============
__global__ __launch_bounds__(512) void k_fmean(const float* __restrict__ hmix, float* __restrict__ fmean){
    int f = blockIdx.x, d = threadIdx.x;
    float s = 0.0f;
    for (int c=0;c<128;++c) s += hmix[(size_t)((f<<7)+c)*HID + d];
    fmean[f*HID + d] = s*(1.0f/128.0f);
}

// ============ faction sync + debate ============
__global__ __launch_bounds__(512) void k_final_h(const float* __restrict__ hmix,
        const float* __restrict__ fmean, const int* __restrict__ stepp, float* __restrict__ hout){
    int cell = blockIdx.x, d = threadIdx.x;
    int f = cell >> 7;
    float v = 0.85f*hmix[(size_t)cell*HID + d] + 0.15f*fmean[f*HID + d];
    if (*stepp > 5 && (cell & 127) < 32){
        float g = 0.0f;
        #pragma unroll
        for (int q=0;q<8;++q) g += fmean[q*HID + d];
        g *= 0.125f;
        v = 0.85f*v + 0.15f*g;
    }
    hout[(size_t)cell*HID + d] = v;
}

// ============ softmax(tension) + avg ============
__global__ __launch_bounds__(1024) void k_softmax(const float* __restrict__ tension,
        float* __restrict__ weights, float* __restrict__ avg_out){
    int t = threadIdx.x;
    int lane = t & 63, wv = t >> 6;
    float tv = tension[t];
    __shared__ float red[16], redb[16], SS[2];
    float m = tv;
    #pragma unroll
    for (int s=1;s<64;s<<=1) m = fmaxf(m, __shfl_xor(m, s));
    if (lane==0) red[wv] = m;
    __syncthreads();
    if (t==0){ float mm=red[0]; for(int i=1;i<16;++i) mm=fmaxf(mm,red[i]); SS[1]=mm; }
    __syncthreads();
    float M = SS[1];
    float ex = expf(tv - M);
    float s2 = ex, s3 = tv;
    #pragma unroll
    for (int s=1;s<64;s<<=1){ s2 += __shfl_xor(s2,s); s3 += __shfl_xor(s3,s); }
    if (lane==0){ red[wv]=s2; redb[wv]=s3; }
    __syncthreads();
    if (t==0){
        float a=0,b=0;
        for(int i=0;i<16;++i){ a+=red[i]; b+=redb[i]; }
        SS[0]=a;
        avg_out[0] = b*(1.0f/1024.0f);
    }
    __syncthreads();
    weights[t] = ex / SS[0];
}

// ============ weighted row-sum partials ============
__global__ __launch_bounds__(256) void k_copart(const float* __restrict__ OUT,
        const float* __restrict__ weights, float* __restrict__ copart){
    int b = blockIdx.x, c = threadIdx.x;
    float s = 0.0f;
    for (int r = b*32; r < b*32+32; ++r) s = fmaf(weights[r], OUT[(size_t)r*ODIM + c], s);
    copart[b*ODIM + c] = s;
}

// ============ head ============
__global__ __launch_bounds__(256) void k_pred(const float* __restrict__ copart,
        const float* __restrict__ head_w, const float* __restrict__ head_b, float* __restrict__ pred){
    int o = threadIdx.x;
    __shared__ float co[ODIM];
    float s = 0.0f;
    for (int b=0;b<32;++b) s += copart[b*ODIM + o];
    co[o] = s;
    __syncthreads();
    float acc = head_b[o];
    for (int c=0;c<ODIM;++c) acc = fmaf(head_w[(size_t)o*ODIM + c], co[c], acc);
    pred[o] = acc;
}

extern "C" void kernel_launch(void* const* d_in, const int* in_sizes, int n_in,
                              void* d_out, int out_size, void* d_ws, size_t ws_size,
                              hipStream_t stream)
{
    const float* x      = (const float*)d_in[0];
    const float* hiddens= (const float*)d_in[1];
    const float* W1a=(const float*)d_in[2];  const float* b1a=(const float*)d_in[3];
    const float* W2a=(const float*)d_in[4];  const float* b2a=(const float*)d_in[5];
    const float* W1g=(const float*)d_in[6];  const float* b1g=(const float*)d_in[7];
    const float* W2g=(const float*)d_in[8];  const float* b2g=(const float*)d_in[9];
    const float* w_ih=(const float*)d_in[10]; const float* w_hh=(const float*)d_in[11];
    const float* b_ih=(const float*)d_in[12]; const float* b_hh=(const float*)d_in[13];
    const float* head_w=(const float*)d_in[14]; const float* head_b=(const float*)d_in[15];
    const float* ent=(const float*)d_in[16]; const float* bell=(const float*)d_in[17];
    const int*   stepp=(const int*)d_in[18];
    float* out = (float*)d_out;

    char* wsb = (char*)d_ws;
    size_t off = 0;
    auto carve = [&](size_t bytes)->char*{ char* p = wsb + off; off += (bytes + 63) & ~(size_t)63; return p; };
    ushort_t* Wc1f  = (ushort_t*)carve((size_t)256*768*2);
    ushort_t* Wc2f  = (ushort_t*)carve((size_t)256*256*2);
    ushort_t* wihf  = (ushort_t*)carve((size_t)1536*256*2);
    ushort_t* whhf  = (ushort_t*)carve((size_t)1536*512*2);
    float* bc1   = (float*)carve(256*4);
    float* bc2   = (float*)carve(256*4);
    float* wcol  = (float*)carve(1536*4);
    float* OUT   = (float*)carve((size_t)1024*256*4);
    float* tension=(float*)carve(1024*4);
    float* GS    = (float*)carve((size_t)1024*1024*4);
    float* GIn   = (float*)carve((size_t)1024*512*4);
    float* GHn   = (float*)carve((size_t)1024*512*4);
    float* hmix  = (float*)carve((size_t)1024*512*4);
    float* fmean = (float*)carve(8*512*4);
    float* weights=(float*)carve(1024*4);
    float* copart =(float*)carve(32*256*4);

    k_cvtw<<<705, 256, 0, stream>>>(W1a, W1g, W2a, W2g, w_ih, w_hh,
                                    b1a, b1g, b2a, b2g,
                                    Wc1f, Wc2f, wihf, whhf, bc1, bc2, wcol);
    k_fwd<<<64, 256, 0, stream>>>(x, hiddens, Wc1f, Wc2f, wihf, whhf,
                                  bc1, bc2, b_ih, b_hh,
                                  OUT, tension, GS, GIn, GHn);
    k_mix<<<512, 512, 0, stream>>>(GS, GIn, GHn, tension, wcol, hiddens, bell, ent, hmix);
    k_fmean<<<8, 512, 0, stream>>>(hmix, fmean);
    k_final_h<<<1024, 512, 0, stream>>>(hmix, fmean, stepp, out + 257);
    k_softmax<<<1, 1024, 0, stream>>>(tension, weights, out + 256);
    k_copart<<<32, 256, 0, stream>>>(OUT, weights, copart);
    k_pred<<<1, 256, 0, stream>>>(copart, head_w, head_b, out);
}